// Round 3
// baseline (207.385 us; speedup 1.0000x reference)
//
#include <hip/hip_runtime.h>
#include <hip/hip_bf16.h>

// Causal MHA: B=4,N=4,L=1024,H=8,E=64, fp32 in/out, bf16 MFMA compute.
// X[b,n,l,h,e] flat = ((bn*L + l)*H + h)*E + e ; head=(bn,h), 128 heads.
//
// ROUND-3 RESTRUCTURE: occupancy. Rounds 0-2 proved all pipes <30% busy at
// 16 waves/CU (VGPR=80 -> 4 waves/SIMD band; grid 1024 = 4 blocks/CU).
// Now: 1 q-tile (64 rows) per block -> grid 2048 = 8 blocks/CU, KVBLK=32
// double-buffered = 16 KB LDS/block (8x16=128<=160 KB), and VGPR forced <=64
// via __launch_bounds__(256,8) -> 8 waves/SIMD -> 32 waves/CU. Register diet:
// o[4]=16, qa[2]=8, prefetch 16 (kpre 2xfloat4 + vpre 8), prefetch issued
// MID-iteration (after softmax, before PV) so kpre/vpre never overlap sacc.
// Same-head blocks still land on one XCD (blk%8 == head%8) -> K/V L2 reuse.
//
// Kept from round 2 (all verified, conflicts = 0): transposed S^T = K.Q^T,
// P in registers via v_permlane32/16_swap into K=32 B-frags (K=16 mfma costs
// the SAME cycles as K=32 -- never use it for bulk FLOPs), XOR-swizzled LDS,
// single lgkm-only barrier per iteration (vmcnt never drained at barriers),
// fixed-max softmax with scale*log2e folded into Q.
// Causal skipping at 32-granularity: fully-masked waves skip QK+PV
// (wave-uniform), staged K/V traffic ~-30% vs 64-wide tiles.

typedef __bf16 bf16x8 __attribute__((ext_vector_type(8)));
typedef __bf16 bf16x4 __attribute__((ext_vector_type(4)));
typedef float  f32x4  __attribute__((ext_vector_type(4)));
typedef unsigned u32x2 __attribute__((ext_vector_type(2)));
typedef unsigned u32x4 __attribute__((ext_vector_type(4)));

#define SEQ 1024
#define ROWSTRIDE 512 // H*E
#define KVB 32        // K/V tile rows per iteration

__device__ inline bf16x8 pack8(float4 a, float4 b) {
    bf16x8 f;
    f[0]=(__bf16)a.x; f[1]=(__bf16)a.y; f[2]=(__bf16)a.z; f[3]=(__bf16)a.w;
    f[4]=(__bf16)b.x; f[5]=(__bf16)b.y; f[6]=(__bf16)b.z; f[7]=(__bf16)b.w;
    return f;
}

__device__ inline bf16x8 pack8s(float4 a, float4 b, float s) {
    bf16x8 f;
    f[0]=(__bf16)(a.x*s); f[1]=(__bf16)(a.y*s); f[2]=(__bf16)(a.z*s); f[3]=(__bf16)(a.w*s);
    f[4]=(__bf16)(b.x*s); f[5]=(__bf16)(b.y*s); f[6]=(__bf16)(b.z*s); f[7]=(__bf16)(b.w*s);
    return f;
}

// LDS-visibility-only barrier: do NOT drain vmcnt (keeps global prefetch
// loads in flight; compiler inserts vmcnt waits at register use).
__device__ inline void lds_barrier() {
    asm volatile("s_waitcnt lgkmcnt(0)\n\ts_barrier" ::: "memory");
}

// gfx950 two-output lane swaps; both operands are modified.
__device__ inline void swap32(unsigned &a, unsigned &b) {
    asm("v_permlane32_swap_b32 %0, %1" : "+v"(a), "+v"(b));
}
__device__ inline void swap16(unsigned &a, unsigned &b) {
    asm("v_permlane16_swap_b32 %0, %1" : "+v"(a), "+v"(b));
}

__global__ __launch_bounds__(256, 8) void attn_fwd(
    const float* __restrict__ Qg,
    const float* __restrict__ Kg,
    const float* __restrict__ Vg,
    float* __restrict__ Og)
{
    // double-buffered, XOR-swizzled 16B blocks.
    // Kds row = 128B = 8 slots: phys = cb ^ (row&7).
    // Vds row =  64B = 4 slots: phys = slot ^ ((row>>1)&3).
    __shared__ __bf16 Kds[2][KVB][64];   // Kds[buf][s][e]
    __shared__ __bf16 Vds[2][64][KVB];   // transposed: Vds[buf][e][s]

    const int blk  = blockIdx.x;
    const int qt   = blk >> 7;        // q-tile 0..15; same-head blocks same XCD
    const int head = blk & 127;
    const int h    = head & 7;
    const int bn   = head >> 3;

    const int tid  = threadIdx.x;
    const int wave = tid >> 6;
    const int lane = tid & 63;
    const int quad = lane >> 4;
    const int l15  = lane & 15;
    const int swz  = l15 & 7;         // K read row-xor (row = c*16+l15)
    const int vswz = (l15 >> 1) & 3;  // V read slot-xor (row = e*16+l15)

    const size_t base = (size_t)bn * SEQ * ROWSTRIDE + (size_t)h * 64;

    // scale * log2(e), folded into Q fragment
    const float kscale = 0.125f * 1.44269504088896f;

    // ---- Q fragments, B-operand layout of 16x16x32 (n=l15 -> q row, k=quad*8+j)
    const int qrow = qt * 64 + wave * 16;
    bf16x8 qa[2];
    {
        const float* qp = Qg + base + (size_t)(qrow + l15) * ROWSTRIDE + quad * 8;
        #pragma unroll
        for (int t = 0; t < 2; ++t)
            qa[t] = pack8s(*(const float4*)(qp + t * 32),
                           *(const float4*)(qp + t * 32 + 4), kscale);
    }

    f32x4 o[4];           // O^T accumulators; lane: q=l15, e=et*16+quad*4+r
    float lsum = 0.f;     // per-lane partial row-sum (lane owns q=l15)
    #pragma unroll
    for (int e = 0; e < 4; ++e) o[e] = (f32x4){0.f, 0.f, 0.f, 0.f};

    // K staging: thread -> row sr (0..31), 16B-block kc (8 per row)
    const int sr = tid >> 3, kc = tid & 7;
    // V staging: thread -> e-column ve, 8 s-rows from wave*8 (free transpose)
    const int ve = tid & 63;

    const int ntiles = 2 * qt + 2;

    const float* kp = Kg + base + (size_t)sr * ROWSTRIDE + kc * 8;
    const float* vp = Vg + base + (size_t)(wave * 8) * ROWSTRIDE + ve;

    // ---- prefetch tile 0 into registers
    float4 kpre[2];
    float  vpre[8];
    kpre[0] = *(const float4*)kp;
    kpre[1] = *(const float4*)(kp + 4);
    #pragma unroll
    for (int j = 0; j < 8; ++j) vpre[j] = vp[(size_t)j * ROWSTRIDE];
    kp += (size_t)KVB * ROWSTRIDE;
    vp += (size_t)KVB * ROWSTRIDE;

    for (int tile = 0; tile < ntiles; ++tile) {
        const int bb = tile & 1;

        // ---- commit prefetched K/V to LDS buf[bb] (bf16, swizzled b128 writes).
        // Reads of buf[bb] were lgkm-drained at the previous barrier.
        *(bf16x8*)&Kds[bb][sr][(kc ^ (sr & 7)) << 3] = pack8(kpre[0], kpre[1]);
        {
            bf16x8 f0;
            #pragma unroll
            for (int jj = 0; jj < 8; ++jj) f0[jj] = (__bf16)vpre[jj];
            *(bf16x8*)&Vds[bb][ve][(wave ^ ((ve >> 1) & 3)) << 3] = f0;
        }

        lds_barrier();   // single barrier per iteration: buf[bb] visible (lgkm only)

        // wave-uniform causal activity: wave's q rows [qrow, qrow+16); tile's s
        // rows [tile*32, tile*32+32). reltile = s0 - qrow.
        const int reltile = tile * 32 - qt * 64 - wave * 16;
        const bool active = reltile < 16;

        bf16x8 pf;       // P B-frag (K=32): P[s = quad*8+j] for q=l15
        if (active) {
            // ---- S^T = K·Q^T (2 c-tiles x 2 k-slabs)
            f32x4 sacc[2];
            __builtin_amdgcn_s_setprio(1);
            #pragma unroll
            for (int c = 0; c < 2; ++c) {
                sacc[c] = (f32x4){0.f, 0.f, 0.f, 0.f};
                #pragma unroll
                for (int t = 0; t < 2; ++t) {
                    bf16x8 kb = *(const bf16x8*)&Kds[bb][c * 16 + l15][((t * 4 + quad) ^ swz) << 3];
                    sacc[c] = __builtin_amdgcn_mfma_f32_16x16x32_bf16(kb, qa[t], sacc[c], 0, 0, 0);
                }
            }
            __builtin_amdgcn_s_setprio(0);

            // ---- exp2 + causal mask + pack to bf16 pairs
            const bool diag = (reltile >= -16);   // masking possible only here
            float ls = 0.f;
            unsigned U[2][2];
            #pragma unroll
            for (int c = 0; c < 2; ++c) {
                bf16x4 pk;
                #pragma unroll
                for (int r = 0; r < 4; ++r) {
                    float p = __builtin_amdgcn_exp2f(sacc[c][r]);
                    // mask: s_loc = c*16+quad*4+r, s_glob > q_glob <=> reltile + s_loc > l15
                    if (diag && (reltile + c * 16 + quad * 4 + r > l15)) p = 0.f;
                    ls += p;
                    pk[r] = (__bf16)p;
                }
                u32x2 uu = __builtin_bit_cast(u32x2, pk);
                U[c][0] = uu[0]; U[c][1] = uu[1];
            }
            lsum += ls;

            // redistribute: lane holds s=16c+4*quad+r -> B-frag needs s=8*quad+j
            unsigned a0 = U[0][0], a1 = U[0][1];
            unsigned b0 = U[1][0], b1 = U[1][1];
            swap32(a0, b0); swap32(a1, b1);
            swap16(a0, b0); swap16(a1, b1);
            u32x4 w; w[0] = a0; w[1] = a1; w[2] = b0; w[3] = b1;
            pf = __builtin_bit_cast(bf16x8, w);
        }

        // ---- issue prefetch for next tile (mid-iteration: kpre/vpre liveness
        // does not overlap sacc; PV + next barrier hide the latency, and 32
        // resident waves/CU absorb any residual stall)
        if (tile + 1 < ntiles) {
            kpre[0] = *(const float4*)kp;
            kpre[1] = *(const float4*)(kp + 4);
            #pragma unroll
            for (int j = 0; j < 8; ++j) vpre[j] = vp[(size_t)j * ROWSTRIDE];
            kp += (size_t)KVB * ROWSTRIDE;
            vp += (size_t)KVB * ROWSTRIDE;
        }

        if (active) {
            // ---- O^T += V^T·P^T : one K=32 MFMA per e-tile
            __builtin_amdgcn_s_setprio(1);
            #pragma unroll
            for (int e = 0; e < 4; ++e) {
                bf16x8 vb = *(const bf16x8*)&Vds[bb][e * 16 + l15][(quad ^ vswz) << 3];
                o[e] = __builtin_amdgcn_mfma_f32_16x16x32_bf16(vb, pf, o[e], 0, 0, 0);
            }
            __builtin_amdgcn_s_setprio(0);
        }
    }

    // ---- epilogue: reduce l across quads (lane owns q=l15), O/l, float4 store
    {
        float s = lsum;
        s += __shfl_xor(s, 16);
        s += __shfl_xor(s, 32);
        const float inv_l = 1.f / s;
        float* op = Og + base + (size_t)(qrow + l15) * ROWSTRIDE + quad * 4;
        #pragma unroll
        for (int e = 0; e < 4; ++e) {
            float4 v;
            v.x = o[e][0] * inv_l;
            v.y = o[e][1] * inv_l;
            v.z = o[e][2] * inv_l;
            v.w = o[e][3] * inv_l;
            *(float4*)(op + e * 16) = v;
        }
    }
}

extern "C" void kernel_launch(void* const* d_in, const int* in_sizes, int n_in,
                              void* d_out, int out_size, void* d_ws, size_t ws_size,
                              hipStream_t stream) {
    const float* Qg = (const float*)d_in[0];
    const float* Kg = (const float*)d_in[1];
    const float* Vg = (const float*)d_in[2];
    float* Og = (float*)d_out;
    // 128 heads x 16 q-tiles = 2048 blocks, 256 threads, 8 blocks/CU
    attn_fwd<<<dim3(2048), dim3(256), 0, stream>>>(Qg, Kg, Vg, Og);
}

// Round 4
// 155.461 us; speedup vs baseline: 1.3340x; 1.3340x over previous
//
#include <hip/hip_runtime.h>
#include <hip/hip_bf16.h>

// Causal MHA: B=4,N=4,L=1024,H=8,E=64, fp32 in/out, bf16 MFMA compute.
// X[b,n,l,h,e] flat = ((bn*L + l)*H + h)*E + e ; head=(bn,h), 128 heads.
//
// ROUND-4: amortization. Rounds 0/2 (16 q/wave, different inner structures)
// both sat at 68us with all pipes <30% busy -> time scales with per-work
// LDS traffic + staged-tile count, not with any single pipe. This version:
// each wave owns 32 q-rows (2 x 16-q groups qh=0,1); every K/V LDS fragment
// is read ONCE and feeds both qh MFMAs -> K/V ds_reads per unit work halved.
// Blocks cover 128 contiguous q-rows -> ntiles = 2qt+2, sum 72 stagings/head
// vs 100 for the round-0/2 pair scheme (-28% iterations at equal work).
// Grid 1024 = 8 q-blocks x 128 heads, 4 blocks/CU; same-head blocks share an
// XCD (blk%8 == head%8) for K/V L2 reuse.
//
// QK is phase-split to cap live registers: phase ph in {0,1} computes c-pair
// {2ph, 2ph+1} (s rows ph*32..ph*32+31) for BOTH qh, then softmax+pack+swap
// into pf[qh][ph] before phase 1 -> sacc peak 16 regs. Causal: the mask can
// hit only the phase with pm = relq+ph*32 == 0 (one sub-tile per wave) ->
// clean path (no cmp/cndmask) everywhere else, wave-uniform branch.
// Phase 1 / PV t=1 skipped entirely when relq >= 0 (upper 32 s all masked).
//
// NO __launch_bounds__ min-waves hint: rounds 1 & 3 proved the allocator
// halves its target under (256,N) and spills 12-16 dwords/thread into the
// main loop (+16-24 MB HBM writes). Plain (256) landed VGPR=80, zero spill.
//
// Kept verified machinery: transposed S^T = K.Q^T (operand swap), P kept in
// registers and redistributed with v_permlane32/16_swap into K=32 B-frags
// (K=16 mfma costs the same cycles as K=32 -- never use it for bulk FLOPs),
// XOR-swizzled K/V LDS (conflicts = 0 measured), double-buffered with a
// single lgkm-only barrier per iteration (vmcnt never drained at barriers),
// fixed-max softmax, scale*log2e folded into Q fragments.

typedef __bf16 bf16x8 __attribute__((ext_vector_type(8)));
typedef __bf16 bf16x4 __attribute__((ext_vector_type(4)));
typedef float  f32x4  __attribute__((ext_vector_type(4)));
typedef unsigned u32x2 __attribute__((ext_vector_type(2)));
typedef unsigned u32x4 __attribute__((ext_vector_type(4)));

#define SEQ 1024
#define ROWSTRIDE 512 // H*E

__device__ inline bf16x8 pack8(float4 a, float4 b) {
    bf16x8 f;
    f[0]=(__bf16)a.x; f[1]=(__bf16)a.y; f[2]=(__bf16)a.z; f[3]=(__bf16)a.w;
    f[4]=(__bf16)b.x; f[5]=(__bf16)b.y; f[6]=(__bf16)b.z; f[7]=(__bf16)b.w;
    return f;
}

__device__ inline bf16x8 pack8s(float4 a, float4 b, float s) {
    bf16x8 f;
    f[0]=(__bf16)(a.x*s); f[1]=(__bf16)(a.y*s); f[2]=(__bf16)(a.z*s); f[3]=(__bf16)(a.w*s);
    f[4]=(__bf16)(b.x*s); f[5]=(__bf16)(b.y*s); f[6]=(__bf16)(b.z*s); f[7]=(__bf16)(b.w*s);
    return f;
}

// LDS-visibility-only barrier: do NOT drain vmcnt (keeps global prefetch
// loads in flight; compiler inserts vmcnt waits at register use).
__device__ inline void lds_barrier() {
    asm volatile("s_waitcnt lgkmcnt(0)\n\ts_barrier" ::: "memory");
}

// gfx950 two-output lane swaps; both operands are modified.
__device__ inline void swap32(unsigned &a, unsigned &b) {
    asm("v_permlane32_swap_b32 %0, %1" : "+v"(a), "+v"(b));
}
__device__ inline void swap16(unsigned &a, unsigned &b) {
    asm("v_permlane16_swap_b32 %0, %1" : "+v"(a), "+v"(b));
}

__global__ __launch_bounds__(256) void attn_fwd(
    const float* __restrict__ Qg,
    const float* __restrict__ Kg,
    const float* __restrict__ Vg,
    float* __restrict__ Og)
{
    // double-buffered, XOR-swizzled (16B blocks): phys_blk = blk ^ (row&7)
    __shared__ __bf16 Kds[2][64][64];   // Kds[buf][s][e]
    __shared__ __bf16 Vds[2][64][64];   // transposed: Vds[buf][e][s]

    const int blk  = blockIdx.x;
    const int qt   = blk >> 7;        // q-block 0..7 (128 q rows each)
    const int head = blk & 127;
    const int h    = head & 7;
    const int bn   = head >> 3;

    const int tid  = threadIdx.x;
    const int wave = tid >> 6;
    const int lane = tid & 63;
    const int quad = lane >> 4;
    const int l15  = lane & 15;
    const int swz  = l15 & 7;         // read-side row-xor ((c*16+l15)&7 == l15&7)

    const size_t base = (size_t)bn * SEQ * ROWSTRIDE + (size_t)h * 64;

    // scale * log2(e), folded into Q fragment
    const float kscale = 0.125f * 1.44269504088896f;

    // ---- Q fragments, B-operand layout of 16x16x32 (n=l15 -> q row, k=quad*8+j)
    const int qrow = qt * 128 + wave * 32;   // wave owns q rows [qrow, qrow+32)
    bf16x8 qa[2][2];                          // [qh][t]
    #pragma unroll
    for (int qh = 0; qh < 2; ++qh) {
        const float* qp = Qg + base + (size_t)(qrow + qh * 16 + l15) * ROWSTRIDE + quad * 8;
        #pragma unroll
        for (int t = 0; t < 2; ++t)
            qa[qh][t] = pack8s(*(const float4*)(qp + t * 32),
                               *(const float4*)(qp + t * 32 + 4), kscale);
    }

    f32x4 o[2][4];        // O^T accumulators [qh][etile]; lane: q=l15, e=et*16+quad*4+r
    float lsum[2] = {0.f, 0.f};
    #pragma unroll
    for (int qh = 0; qh < 2; ++qh)
        #pragma unroll
        for (int e = 0; e < 4; ++e) o[qh][e] = (f32x4){0.f, 0.f, 0.f, 0.f};

    // K staging: thread -> row sr, 16B-blocks cbk, cbk+1 (16 cols from cbk*8)
    const int sr = tid >> 2, cbk = (tid & 3) << 1;
    // V staging: thread -> one e-column ve, 16 s-rows from cbv*8 (free transpose)
    const int ve = tid & 63, cbv = (tid >> 6) << 1;

    const int ntiles = 2 * qt + 2;

    const float* kp = Kg + base + (size_t)sr * ROWSTRIDE + (cbk << 3);
    const float* vp = Vg + base + (size_t)(cbv << 3) * ROWSTRIDE + ve;

    // ---- prefetch tile 0 into registers
    float4 kpre[4];
    float  vpre[16];
    #pragma unroll
    for (int i = 0; i < 4; ++i) kpre[i] = *(const float4*)(kp + i * 4);
    #pragma unroll
    for (int j = 0; j < 16; ++j) vpre[j] = vp[(size_t)j * ROWSTRIDE];
    kp += (size_t)64 * ROWSTRIDE;
    vp += (size_t)64 * ROWSTRIDE;

    for (int tile = 0; tile < ntiles; ++tile) {
        const int bb = tile & 1;

        // ---- commit prefetched K/V to LDS buf[bb] (bf16, swizzled b128 writes).
        // Reads of buf[bb] were lgkm-drained at the previous barrier.
        {
            const int rk = sr & 7;
            *(bf16x8*)&Kds[bb][sr][(cbk ^ rk) << 3]       = pack8(kpre[0], kpre[1]);
            *(bf16x8*)&Kds[bb][sr][((cbk + 1) ^ rk) << 3] = pack8(kpre[2], kpre[3]);
            bf16x8 f0, f1;
            #pragma unroll
            for (int jj = 0; jj < 8; ++jj) { f0[jj] = (__bf16)vpre[jj]; f1[jj] = (__bf16)vpre[8 + jj]; }
            const int rv = ve & 7;
            *(bf16x8*)&Vds[bb][ve][(cbv ^ rv) << 3]       = f0;
            *(bf16x8*)&Vds[bb][ve][((cbv + 1) ^ rv) << 3] = f1;
        }

        // ---- issue prefetch for next tile (in flight through barrier+compute)
        if (tile + 1 < ntiles) {
            #pragma unroll
            for (int i = 0; i < 4; ++i) kpre[i] = *(const float4*)(kp + i * 4);
            #pragma unroll
            for (int j = 0; j < 16; ++j) vpre[j] = vp[(size_t)j * ROWSTRIDE];
            kp += (size_t)64 * ROWSTRIDE;
            vp += (size_t)64 * ROWSTRIDE;
        }

        lds_barrier();   // single barrier per iteration: buf[bb] visible (lgkm only)

        // wave-uniform causal state: relq = s0 - qrow; multiples of 32.
        const int relq = tile * 64 - qrow;
        const bool active   = relq < 32;   // some s in this tile is needed
        const bool hiActive = relq < 0;    // upper 32 s rows not fully masked

        bf16x8 pf[2][2];   // P B-frags [qh][t]: P[s=t*32+quad*8+j] for q=l15

        // phase ph: c-pair {2ph,2ph+1} (s rows ph*32..+31) for BOTH qh, then
        // softmax+pack+permlane into pf[qh][ph]. sacc peak = 16 regs.
        auto phase = [&](int ph) {
            f32x4 sacc[2][2];   // [qh][cl]
            #pragma unroll
            for (int qh = 0; qh < 2; ++qh)
                #pragma unroll
                for (int cl = 0; cl < 2; ++cl) sacc[qh][cl] = (f32x4){0.f, 0.f, 0.f, 0.f};
            __builtin_amdgcn_s_setprio(1);
            #pragma unroll
            for (int cl = 0; cl < 2; ++cl) {
                #pragma unroll
                for (int t = 0; t < 2; ++t) {
                    bf16x8 kb = *(const bf16x8*)&Kds[bb][(ph * 2 + cl) * 16 + l15][((t * 4 + quad) ^ swz) << 3];
                    // operand swap: A=K, B=Q -> D = S^T; one kb feeds both qh
                    sacc[0][cl] = __builtin_amdgcn_mfma_f32_16x16x32_bf16(kb, qa[0][t], sacc[0][cl], 0, 0, 0);
                    sacc[1][cl] = __builtin_amdgcn_mfma_f32_16x16x32_bf16(kb, qa[1][t], sacc[1][cl], 0, 0, 0);
                }
            }
            __builtin_amdgcn_s_setprio(0);
            // mask possible only when this phase sits on the diagonal: pm == 0
            const int pm = relq + ph * 32;
            #pragma unroll
            for (int qh = 0; qh < 2; ++qh) {
                unsigned U[2][2];
                float ls = 0.f;
                if (pm == 0) {
                    #pragma unroll
                    for (int cl = 0; cl < 2; ++cl) {
                        bf16x4 pk;
                        #pragma unroll
                        for (int r = 0; r < 4; ++r) {
                            float p = __builtin_amdgcn_exp2f(sacc[qh][cl][r]);
                            // s_loc = cl*16+quad*4+r > q_loc = qh*16+l15 -> masked
                            if (cl * 16 + quad * 4 + r > qh * 16 + l15) p = 0.f;
                            ls += p; pk[r] = (__bf16)p;
                        }
                        u32x2 uu = __builtin_bit_cast(u32x2, pk);
                        U[cl][0] = uu[0]; U[cl][1] = uu[1];
                    }
                } else {            // pm <= -32: fully unmasked, no cmp/cndmask
                    #pragma unroll
                    for (int cl = 0; cl < 2; ++cl) {
                        bf16x4 pk;
                        #pragma unroll
                        for (int r = 0; r < 4; ++r) {
                            float p = __builtin_amdgcn_exp2f(sacc[qh][cl][r]);
                            ls += p; pk[r] = (__bf16)p;
                        }
                        u32x2 uu = __builtin_bit_cast(u32x2, pk);
                        U[cl][0] = uu[0]; U[cl][1] = uu[1];
                    }
                }
                lsum[qh] += ls;
                // redistribute: lane holds s=16cl+4*quad+r -> frag needs s=8*quad+j
                unsigned a0 = U[0][0], a1 = U[0][1];
                unsigned b0 = U[1][0], b1 = U[1][1];
                swap32(a0, b0); swap32(a1, b1);
                swap16(a0, b0); swap16(a1, b1);
                u32x4 w; w[0] = a0; w[1] = a1; w[2] = b0; w[3] = b1;
                pf[qh][ph] = __builtin_bit_cast(bf16x8, w);
            }
        };

        if (active) {
            phase(0);
            if (hiActive) phase(1);

            // ---- O^T += V^T·P^T : K=32 MFMA; each vb feeds both qh
            __builtin_amdgcn_s_setprio(1);
            #pragma unroll
            for (int e = 0; e < 4; ++e) {
                bf16x8 vb0 = *(const bf16x8*)&Vds[bb][e * 16 + l15][(quad ^ swz) << 3];
                o[0][e] = __builtin_amdgcn_mfma_f32_16x16x32_bf16(vb0, pf[0][0], o[0][e], 0, 0, 0);
                o[1][e] = __builtin_amdgcn_mfma_f32_16x16x32_bf16(vb0, pf[1][0], o[1][e], 0, 0, 0);
                if (hiActive) {
                    bf16x8 vb1 = *(const bf16x8*)&Vds[bb][e * 16 + l15][((4 + quad) ^ swz) << 3];
                    o[0][e] = __builtin_amdgcn_mfma_f32_16x16x32_bf16(vb1, pf[0][1], o[0][e], 0, 0, 0);
                    o[1][e] = __builtin_amdgcn_mfma_f32_16x16x32_bf16(vb1, pf[1][1], o[1][e], 0, 0, 0);
                }
            }
            __builtin_amdgcn_s_setprio(0);
        }
    }

    // ---- epilogue: reduce l across quads (lane owns q=l15), O/l, float4 store
    #pragma unroll
    for (int qh = 0; qh < 2; ++qh) {
        float s = lsum[qh];
        s += __shfl_xor(s, 16);
        s += __shfl_xor(s, 32);
        const float inv_l = 1.f / s;
        float* op = Og + base + (size_t)(qrow + qh * 16 + l15) * ROWSTRIDE + quad * 4;
        #pragma unroll
        for (int e = 0; e < 4; ++e) {
            float4 v;
            v.x = o[qh][e][0] * inv_l;
            v.y = o[qh][e][1] * inv_l;
            v.z = o[qh][e][2] * inv_l;
            v.w = o[qh][e][3] * inv_l;
            *(float4*)(op + e * 16) = v;
        }
    }
}

extern "C" void kernel_launch(void* const* d_in, const int* in_sizes, int n_in,
                              void* d_out, int out_size, void* d_ws, size_t ws_size,
                              hipStream_t stream) {
    const float* Qg = (const float*)d_in[0];
    const float* Kg = (const float*)d_in[1];
    const float* Vg = (const float*)d_in[2];
    float* Og = (float*)d_out;
    // 128 heads x 8 q-blocks (128 q rows each) = 1024 blocks, 256 threads
    attn_fwd<<<dim3(1024), dim3(256), 0, stream>>>(Qg, Kg, Vg, Og);
}

// Round 6
// 146.314 us; speedup vs baseline: 1.4174x; 1.0625x over previous
//
#include <hip/hip_runtime.h>
#include <hip/hip_bf16.h>

// Causal MHA: B=4,N=4,L=1024,H=8,E=64, fp32 in/out, bf16 MFMA compute.
// X[b,n,l,h,e] flat = ((bn*L + l)*H + h)*E + e ; head=(bn,h), 128 heads.
//
// ROUND-6: R5's structure (512 threads / 8 waves / 256 q-rows per block /
// 40 stagings per head) with the bug surface removed. R5 failed correctness
// with inner compute byte-identical to the passing R4; the only new code was
// a phase lambda with runtime-indexed pf[qh][ph] and uninitialized pf on
// skipped phases (undef feeding speculatable pure MFMA). This version:
//  - phases written out explicitly, no lambda, no runtime array indexing;
//  - pf split into four NAMED registers, zero-initialized;
//  - softmax/pack/permlane in a plain inline helper (compile-time structure);
//  - simple balanced dispatch: qt = blk<256 ? blk>>7 : 3-((blk&255)>>7),
//    so round-robin co-resident pairs (c, c+256) carry complementary weights
//    (4+16 / 8+12 = 20 units per CU); head = blk&127 keeps a head's blocks
//    on one XCD.
//
// Why this structure: R4 (-12%) proved per-work amortization is the lever.
// Here each staged 64-row K/V tile feeds 8 waves x 2 q-groups; stagings/head
// 72 -> 40; every LDS fragment read feeds 2 MFMAs.
//
// NO __launch_bounds__ min-waves hint: rounds 1 & 3 proved the allocator
// over-shrinks and spills 12-16 dwords/thread (+16-24 MB HBM writes).
//
// Kept verified machinery: transposed S^T = K.Q^T (operand swap), P kept in
// registers and redistributed with v_permlane32/16_swap into K=32 B-frags
// (K=16 mfma costs the same cycles as K=32 -- never use it for bulk FLOPs),
// XOR-swizzled K/V LDS (conflicts = 0 measured), double-buffered with a
// single lgkm-only barrier per iteration (vmcnt never drained at barriers),
// diag mask only on the pm==0 sub-tile, fixed-max softmax, scale*log2e
// folded into Q fragments.

typedef __bf16 bf16x8 __attribute__((ext_vector_type(8)));
typedef __bf16 bf16x4 __attribute__((ext_vector_type(4)));
typedef float  f32x4  __attribute__((ext_vector_type(4)));
typedef unsigned u32x2 __attribute__((ext_vector_type(2)));
typedef unsigned u32x4 __attribute__((ext_vector_type(4)));

#define SEQ 1024
#define ROWSTRIDE 512 // H*E

__device__ inline bf16x8 pack8(float4 a, float4 b) {
    bf16x8 f;
    f[0]=(__bf16)a.x; f[1]=(__bf16)a.y; f[2]=(__bf16)a.z; f[3]=(__bf16)a.w;
    f[4]=(__bf16)b.x; f[5]=(__bf16)b.y; f[6]=(__bf16)b.z; f[7]=(__bf16)b.w;
    return f;
}

__device__ inline bf16x8 pack8s(float4 a, float4 b, float s) {
    bf16x8 f;
    f[0]=(__bf16)(a.x*s); f[1]=(__bf16)(a.y*s); f[2]=(__bf16)(a.z*s); f[3]=(__bf16)(a.w*s);
    f[4]=(__bf16)(b.x*s); f[5]=(__bf16)(b.y*s); f[6]=(__bf16)(b.z*s); f[7]=(__bf16)(b.w*s);
    return f;
}

// LDS-visibility-only barrier: do NOT drain vmcnt (keeps global prefetch
// loads in flight; compiler inserts vmcnt waits at register use).
__device__ inline void lds_barrier() {
    asm volatile("s_waitcnt lgkmcnt(0)\n\ts_barrier" ::: "memory");
}

// gfx950 two-output lane swaps; both operands are modified.
__device__ inline void swap32(unsigned &a, unsigned &b) {
    asm("v_permlane32_swap_b32 %0, %1" : "+v"(a), "+v"(b));
}
__device__ inline void swap16(unsigned &a, unsigned &b) {
    asm("v_permlane16_swap_b32 %0, %1" : "+v"(a), "+v"(b));
}

// exp2 + optional causal mask + pack + cross-quad redistribute for one
// (q-group, s-half). Input: sA/sB = S^T c-tiles cl=0/1 (lane: q=l15,
// s_loc = cl*16 + quad*4 + r). Output: B-frag of 16x16x32 holding
// P[s_loc = quad*8 + j] for q = l15. Masked lanes: s_loc > qloc when diag.
__device__ inline bf16x8 softmax_pack(f32x4 sA, f32x4 sB, bool diag,
                                      int qloc, int quad, float &ls)
{
    unsigned U0a, U0b, U1a, U1b;
    {
        bf16x4 pk;
        #pragma unroll
        for (int r = 0; r < 4; ++r) {
            float p = __builtin_amdgcn_exp2f(sA[r]);
            p = (diag && (quad * 4 + r > qloc)) ? 0.f : p;
            ls += p; pk[r] = (__bf16)p;
        }
        u32x2 uu = __builtin_bit_cast(u32x2, pk);
        U0a = uu[0]; U0b = uu[1];
    }
    {
        bf16x4 pk;
        #pragma unroll
        for (int r = 0; r < 4; ++r) {
            float p = __builtin_amdgcn_exp2f(sB[r]);
            p = (diag && (16 + quad * 4 + r > qloc)) ? 0.f : p;
            ls += p; pk[r] = (__bf16)p;
        }
        u32x2 uu = __builtin_bit_cast(u32x2, pk);
        U1a = uu[0]; U1b = uu[1];
    }
    // lane holds s=16cl+4*quad+r -> frag needs s=8*quad+j
    swap32(U0a, U1a); swap32(U0b, U1b);
    swap16(U0a, U1a); swap16(U0b, U1b);
    u32x4 w; w[0] = U0a; w[1] = U0b; w[2] = U1a; w[3] = U1b;
    return __builtin_bit_cast(bf16x8, w);
}

__global__ __launch_bounds__(512) void attn_fwd(
    const float* __restrict__ Qg,
    const float* __restrict__ Kg,
    const float* __restrict__ Vg,
    float* __restrict__ Og)
{
    // double-buffered, XOR-swizzled (16B blocks): phys_blk = blk ^ (row&7)
    __shared__ __bf16 Kds[2][64][64];   // Kds[buf][s][e]
    __shared__ __bf16 Vds[2][64][64];   // transposed: Vds[buf][e][s]

    const int blk  = blockIdx.x;
    const int head = blk & 127;
    const int h    = head & 7;
    const int bn   = head >> 3;
    // complementary-weight pairing for co-resident blocks (c, c+256):
    // qt in {0,1} for blk<256, {3,2} for blk>=256 -> per-CU weight ~20 units
    const int qt   = (blk < 256) ? (blk >> 7) : (3 - ((blk & 255) >> 7));

    const int tid  = threadIdx.x;
    const int wave = tid >> 6;          // 0..7
    const int lane = tid & 63;
    const int quad = lane >> 4;
    const int l15  = lane & 15;
    const int swz  = l15 & 7;           // read-side row-xor ((x*16+l15)&7 == l15&7)

    const size_t base = (size_t)bn * SEQ * ROWSTRIDE + (size_t)h * 64;

    // scale * log2(e), folded into Q fragment
    const float kscale = 0.125f * 1.44269504088896f;

    // ---- Q fragments, B-operand layout of 16x16x32 (n=l15 -> q row, k=quad*8+j)
    const int qrow = qt * 256 + wave * 32;   // wave owns q rows [qrow, qrow+32)
    bf16x8 qa[2][2];                          // [qh][t]
    #pragma unroll
    for (int qh = 0; qh < 2; ++qh) {
        const float* qp = Qg + base + (size_t)(qrow + qh * 16 + l15) * ROWSTRIDE + quad * 8;
        #pragma unroll
        for (int t = 0; t < 2; ++t)
            qa[qh][t] = pack8s(*(const float4*)(qp + t * 32),
                               *(const float4*)(qp + t * 32 + 4), kscale);
    }

    f32x4 o[2][4];        // O^T accumulators [qh][etile]; lane: q=l15, e=et*16+quad*4+r
    float lsum0 = 0.f, lsum1 = 0.f;
    #pragma unroll
    for (int qh = 0; qh < 2; ++qh)
        #pragma unroll
        for (int e = 0; e < 4; ++e) o[qh][e] = (f32x4){0.f, 0.f, 0.f, 0.f};

    // K staging: thread -> row sr (0..63), 16B-block kc (0..7): 8 floats each
    const int sr = tid >> 3, kc = tid & 7;
    // V staging: thread -> e-column ve, 8 s-rows from wave*8 (free transpose)
    const int ve = tid & 63;

    const int ntiles = 4 * qt + 4;

    const float* kp = Kg + base + (size_t)sr * ROWSTRIDE + kc * 8;
    const float* vp = Vg + base + (size_t)(wave * 8) * ROWSTRIDE + ve;

    // ---- prefetch tile 0 into registers
    float4 kpre[2];
    float  vpre[8];
    kpre[0] = *(const float4*)kp;
    kpre[1] = *(const float4*)(kp + 4);
    #pragma unroll
    for (int j = 0; j < 8; ++j) vpre[j] = vp[(size_t)j * ROWSTRIDE];
    kp += (size_t)64 * ROWSTRIDE;
    vp += (size_t)64 * ROWSTRIDE;

    for (int tile = 0; tile < ntiles; ++tile) {
        const int bb = tile & 1;

        // ---- commit prefetched K/V to LDS buf[bb] (bf16, swizzled b128 writes).
        // Reads of buf[bb] were lgkm-drained at the previous barrier.
        *(bf16x8*)&Kds[bb][sr][(kc ^ (sr & 7)) << 3] = pack8(kpre[0], kpre[1]);
        {
            bf16x8 f0;
            #pragma unroll
            for (int jj = 0; jj < 8; ++jj) f0[jj] = (__bf16)vpre[jj];
            *(bf16x8*)&Vds[bb][ve][(wave ^ (ve & 7)) << 3] = f0;
        }

        // ---- issue prefetch for next tile (in flight through barrier+compute)
        if (tile + 1 < ntiles) {
            kpre[0] = *(const float4*)kp;
            kpre[1] = *(const float4*)(kp + 4);
            #pragma unroll
            for (int j = 0; j < 8; ++j) vpre[j] = vp[(size_t)j * ROWSTRIDE];
            kp += (size_t)64 * ROWSTRIDE;
            vp += (size_t)64 * ROWSTRIDE;
        }

        lds_barrier();   // single barrier per iteration: buf[bb] visible (lgkm only)

        // wave-uniform causal state: relq = s0 - qrow (multiple of 32).
        const int relq = tile * 64 - qrow;
        const bool active   = relq < 32;   // some s in this tile is needed
        const bool hiActive = relq < 0;    // upper 32 s rows not fully masked

        // P B-frags, named + zero-init (no runtime indexing, no undef paths):
        // pfQH_T holds P[s = T*32 + quad*8 + j] for q-group QH.
        bf16x8 pf00 = {}, pf01 = {}, pf10 = {}, pf11 = {};

        if (active) {
            // ======== phase 0: s rows 0..31 of this tile ========
            {
                f32x4 s00 = (f32x4){0.f,0.f,0.f,0.f}, s01 = (f32x4){0.f,0.f,0.f,0.f};
                f32x4 s10 = (f32x4){0.f,0.f,0.f,0.f}, s11 = (f32x4){0.f,0.f,0.f,0.f};
                __builtin_amdgcn_s_setprio(1);
                #pragma unroll
                for (int t = 0; t < 2; ++t) {
                    bf16x8 kb0 = *(const bf16x8*)&Kds[bb][ 0 + l15][((t * 4 + quad) ^ swz) << 3];
                    bf16x8 kb1 = *(const bf16x8*)&Kds[bb][16 + l15][((t * 4 + quad) ^ swz) << 3];
                    // operand swap: A=K, B=Q -> D = S^T; each kb feeds both qh
                    s00 = __builtin_amdgcn_mfma_f32_16x16x32_bf16(kb0, qa[0][t], s00, 0, 0, 0);
                    s10 = __builtin_amdgcn_mfma_f32_16x16x32_bf16(kb0, qa[1][t], s10, 0, 0, 0);
                    s01 = __builtin_amdgcn_mfma_f32_16x16x32_bf16(kb1, qa[0][t], s01, 0, 0, 0);
                    s11 = __builtin_amdgcn_mfma_f32_16x16x32_bf16(kb1, qa[1][t], s11, 0, 0, 0);
                }
                __builtin_amdgcn_s_setprio(0);
                const bool diag0 = (relq == 0);
                pf00 = softmax_pack(s00, s01, diag0, l15,      quad, lsum0);
                pf10 = softmax_pack(s10, s11, diag0, 16 + l15, quad, lsum1);
            }
            // ======== phase 1: s rows 32..63 of this tile ========
            if (hiActive) {
                f32x4 s00 = (f32x4){0.f,0.f,0.f,0.f}, s01 = (f32x4){0.f,0.f,0.f,0.f};
                f32x4 s10 = (f32x4){0.f,0.f,0.f,0.f}, s11 = (f32x4){0.f,0.f,0.f,0.f};
                __builtin_amdgcn_s_setprio(1);
                #pragma unroll
                for (int t = 0; t < 2; ++t) {
                    bf16x8 kb0 = *(const bf16x8*)&Kds[bb][32 + l15][((t * 4 + quad) ^ swz) << 3];
                    bf16x8 kb1 = *(const bf16x8*)&Kds[bb][48 + l15][((t * 4 + quad) ^ swz) << 3];
                    s00 = __builtin_amdgcn_mfma_f32_16x16x32_bf16(kb0, qa[0][t], s00, 0, 0, 0);
                    s10 = __builtin_amdgcn_mfma_f32_16x16x32_bf16(kb0, qa[1][t], s10, 0, 0, 0);
                    s01 = __builtin_amdgcn_mfma_f32_16x16x32_bf16(kb1, qa[0][t], s01, 0, 0, 0);
                    s11 = __builtin_amdgcn_mfma_f32_16x16x32_bf16(kb1, qa[1][t], s11, 0, 0, 0);
                }
                __builtin_amdgcn_s_setprio(0);
                const bool diag1 = (relq == -32);
                pf01 = softmax_pack(s00, s01, diag1, l15,      quad, lsum0);
                pf11 = softmax_pack(s10, s11, diag1, 16 + l15, quad, lsum1);
            }

            // ======== PV: O^T += V^T.P^T, K=32 MFMA; each vb feeds both qh ====
            __builtin_amdgcn_s_setprio(1);
            #pragma unroll
            for (int e = 0; e < 4; ++e) {
                bf16x8 vb0 = *(const bf16x8*)&Vds[bb][e * 16 + l15][(quad ^ swz) << 3];
                o[0][e] = __builtin_amdgcn_mfma_f32_16x16x32_bf16(vb0, pf00, o[0][e], 0, 0, 0);
                o[1][e] = __builtin_amdgcn_mfma_f32_16x16x32_bf16(vb0, pf10, o[1][e], 0, 0, 0);
                if (hiActive) {
                    bf16x8 vb1 = *(const bf16x8*)&Vds[bb][e * 16 + l15][((4 + quad) ^ swz) << 3];
                    o[0][e] = __builtin_amdgcn_mfma_f32_16x16x32_bf16(vb1, pf01, o[0][e], 0, 0, 0);
                    o[1][e] = __builtin_amdgcn_mfma_f32_16x16x32_bf16(vb1, pf11, o[1][e], 0, 0, 0);
                }
            }
            __builtin_amdgcn_s_setprio(0);
        }
    }

    // ---- epilogue: reduce l across quads (lane owns q=l15), O/l, float4 store
    #pragma unroll
    for (int qh = 0; qh < 2; ++qh) {
        float s = qh ? lsum1 : lsum0;
        s += __shfl_xor(s, 16);
        s += __shfl_xor(s, 32);
        const float inv_l = 1.f / s;
        float* op = Og + base + (size_t)(qrow + qh * 16 + l15) * ROWSTRIDE + quad * 4;
        #pragma unroll
        for (int e = 0; e < 4; ++e) {
            float4 v;
            v.x = o[qh][e][0] * inv_l;
            v.y = o[qh][e][1] * inv_l;
            v.z = o[qh][e][2] * inv_l;
            v.w = o[qh][e][3] * inv_l;
            *(float4*)(op + e * 16) = v;
        }
    }
}

extern "C" void kernel_launch(void* const* d_in, const int* in_sizes, int n_in,
                              void* d_out, int out_size, void* d_ws, size_t ws_size,
                              hipStream_t stream) {
    const float* Qg = (const float*)d_in[0];
    const float* Kg = (const float*)d_in[1];
    const float* Vg = (const float*)d_in[2];
    float* Og = (float*)d_out;
    // 128 heads x 4 q-ranges (256 q rows each) = 512 blocks, 512 threads.
    attn_fwd<<<dim3(512), dim3(512), 0, stream>>>(Qg, Kg, Vg, Og);
}